// Round 4
// baseline (7298.582 us; speedup 1.0000x reference)
//
#include <hip/hip_runtime.h>
#include <math.h>

// GRU-RCN, persistent-kernel version. B=8,T=16,C=Oh=64,HxW=56x56, 3x3 SAME.
// One kernel, 448 blocks co-resident, device-scope atomic grid barrier.
// Pipeline per step t:
//   phase A: convU(t) -> z, r*h    and  xprep(t+1)  (independent)
//   phase B: convC(t) -> h_new,out and  convW(t+1)  (independent)
// Layouts:
//   padded imgs (xb0/xb1/hpad/rhpad): bf16 [b][58][66][64ci], 16B ci-slices
//     XOR-swizzled by (col&7) so LDS ds_read_b128 is bank-conflict-free.
//   wcat: bf16 [plane(ky*3+kx)][o][ci]  (W:192, U:128, C:64)
//   wx0/wx1: bf16 [b][y][px64][192]; zb/hstate: f32 [b][y][px64][64]

#define NBLK 448
#define PIX 4224              // 66*64 ushorts per padded row
#define PIMG 244992           // 58*PIX ushorts per padded image
#define HL_OFF ((size_t)25690112)  // 8*16*64*3136

typedef unsigned short u16;
typedef __attribute__((ext_vector_type(8))) __bf16 bf16x8;
typedef __attribute__((ext_vector_type(4))) float f32x4;

__device__ __forceinline__ float bf2f(u16 u) {
  unsigned v = ((unsigned)u) << 16;
  float f;
  __builtin_memcpy(&f, &v, 4);
  return f;
}
__device__ __forceinline__ u16 f2bf(float f) {
  unsigned u;
  __builtin_memcpy(&u, &f, 4);
  u = (u + 0x7FFFu + ((u >> 16) & 1u)) >> 16;  // RNE
  return (u16)u;
}
__device__ __forceinline__ void gll16(const void* g, void* l) {
  __builtin_amdgcn_global_load_lds(
      (const __attribute__((address_space(1))) void*)g,
      (__attribute__((address_space(3))) void*)l, 16, 0, 0);
}

// ---- device-scope grid barrier (all 448 blocks co-resident) ----------------
__device__ __forceinline__ void gridbar(unsigned* bar) {
  __threadfence();  // release my stores (agent scope; cross-XCD L2 wb)
  __syncthreads();
  if (threadIdx.x == 0) {
    unsigned* cnt = bar;
    unsigned* gen = bar + 1;
    unsigned g = __hip_atomic_load(gen, __ATOMIC_ACQUIRE, __HIP_MEMORY_SCOPE_AGENT);
    unsigned a = __hip_atomic_fetch_add(cnt, 1u, __ATOMIC_ACQ_REL,
                                        __HIP_MEMORY_SCOPE_AGENT);
    if (a == NBLK - 1u) {
      __hip_atomic_store(cnt, 0u, __ATOMIC_RELAXED, __HIP_MEMORY_SCOPE_AGENT);
      __hip_atomic_store(gen, g + 1u, __ATOMIC_RELEASE, __HIP_MEMORY_SCOPE_AGENT);
    } else {
      unsigned iter = 0;
      while (__hip_atomic_load(gen, __ATOMIC_ACQUIRE,
                               __HIP_MEMORY_SCOPE_AGENT) == g) {
        __builtin_amdgcn_s_sleep(2);
        if (++iter > (1u << 22)) break;  // safety valve: fail loud, not hang
      }
    }
  }
  __syncthreads();
  __threadfence();  // acquire: invalidate stale cache lines
}

// ---- conv core: D[32px x NF*16ch per wave] = conv3x3(img, wb), K=576 -------
template <int NF>
__device__ __forceinline__ void conv_core(const u16* __restrict__ img,
                                          const u16* __restrict__ wb,
                                          const int NCH, const int y,
                                          const int x0, const int n0,
                                          u16* stage, f32x4 (&acc)[2][NF]) {
  const int lane = threadIdx.x & 63;
  const int wv = threadIdx.x >> 6;
  __syncthreads();  // protect LDS stage reuse across units
  const u16* wrow = wb + (size_t)(n0 + (lane & 15)) * 64 + ((lane >> 4) * 8);
#define BPTR(ky, kx, kc, nf) \
  (wrow + (size_t)((ky) * 3 + (kx)) * NCH * 64 + (nf) * 1024 + (kc) * 32)
  bf16x8 bcur[3][NF], bnxt[3][NF];
#pragma unroll
  for (int kx = 0; kx < 3; ++kx)
#pragma unroll
    for (int nf = 0; nf < NF; ++nf)
      bcur[kx][nf] = *(const bf16x8*)BPTR(0, kx, 0, nf);

  // stage strip rows y..y+2, cols x0..x0+33 (34px x 128B per row)
#pragma unroll
  for (int i = wv; i < 15; i += 4) {
    const int r = i / 5, k = i % 5;
    const u16* g = img + (size_t)(y + r) * PIX + x0 * 64 + k * 512 + lane * 8;
    u16* l = stage + r * 2176 + k * 512;
    if (k < 4 || lane < 16) gll16(g, l);
  }
  asm volatile("s_waitcnt vmcnt(0)" ::: "memory");
  __syncthreads();

#pragma unroll 1
  for (int kk = 0; kk < 6; ++kk) {
    const int ky = kk >> 1, kc = kk & 1;
    if (kk < 5) {
      const int ky2 = (kk + 1) >> 1, kc2 = (kk + 1) & 1;
#pragma unroll
      for (int kx = 0; kx < 3; ++kx)
#pragma unroll
        for (int nf = 0; nf < NF; ++nf)
          bnxt[kx][nf] = *(const bf16x8*)BPTR(ky2, kx, kc2, nf);
    }
    bf16x8 afr[2][3];
#pragma unroll
    for (int mf = 0; mf < 2; ++mf)
#pragma unroll
      for (int kx = 0; kx < 3; ++kx) {
        const int p = mf * 16 + (lane & 15) + kx;
        const int sl = (kc * 4 + (lane >> 4)) ^ (p & 7);
        afr[mf][kx] = *(const bf16x8*)(stage + (ky * 34 + p) * 64 + sl * 8);
      }
#pragma unroll
    for (int kx = 0; kx < 3; ++kx)
#pragma unroll
      for (int mf = 0; mf < 2; ++mf)
#pragma unroll
        for (int nf = 0; nf < NF; ++nf)
          acc[mf][nf] = __builtin_amdgcn_mfma_f32_16x16x32_bf16(
              afr[mf][kx], bcur[kx][nf], acc[mf][nf], 0, 0, 0);
#pragma unroll
    for (int kx = 0; kx < 3; ++kx)
#pragma unroll
      for (int nf = 0; nf < NF; ++nf)
        bcur[kx][nf] = bnxt[kx][nf];
  }
#undef BPTR
}

// ---- conv unit wrappers (u in [0,896): xt=u&1, row=u>>1 -> y,b) ------------
__device__ __forceinline__ void do_convW(const u16* __restrict__ xp,
                                         const u16* __restrict__ wcat,
                                         u16* __restrict__ wx, int u,
                                         u16* stage) {
  const int x0 = (u & 1) * 32, row = u >> 1;
  const int y = row % 56, b = row / 56;
  const int lane = threadIdx.x & 63;
  const int n0 = __builtin_amdgcn_readfirstlane((threadIdx.x >> 6) * 48);
  f32x4 acc[2][3];
#pragma unroll
  for (int mf = 0; mf < 2; ++mf)
#pragma unroll
    for (int nf = 0; nf < 3; ++nf) acc[mf][nf] = (f32x4){0.f, 0.f, 0.f, 0.f};
  conv_core<3>(xp + (size_t)b * PIMG, wcat, 192, y, x0, n0, stage, acc);
  const size_t rowb = ((size_t)(b * 56) + y) * 64;
#pragma unroll
  for (int mf = 0; mf < 2; ++mf)
#pragma unroll
    for (int nf = 0; nf < 3; ++nf) {
      const int n = n0 + nf * 16 + (lane & 15);
#pragma unroll
      for (int r = 0; r < 4; ++r) {
        const int px = x0 + mf * 16 + 4 * (lane >> 4) + r;
        wx[(rowb + px) * 192 + n] = f2bf(acc[mf][nf][r]);
      }
    }
}

__device__ __forceinline__ void do_convU(const u16* __restrict__ hpad,
                                         const u16* __restrict__ ucat,
                                         const u16* __restrict__ wx,
                                         const float* __restrict__ hstate,
                                         float* __restrict__ zb,
                                         u16* __restrict__ rhpad, int u,
                                         u16* stage) {
  const int x0 = (u & 1) * 32, row = u >> 1;
  const int y = row % 56, b = row / 56;
  const int lane = threadIdx.x & 63;
  const int n0 = __builtin_amdgcn_readfirstlane((threadIdx.x >> 6) * 32);
  f32x4 acc[2][2];
#pragma unroll
  for (int mf = 0; mf < 2; ++mf)
#pragma unroll
    for (int nf = 0; nf < 2; ++nf) acc[mf][nf] = (f32x4){0.f, 0.f, 0.f, 0.f};
  conv_core<2>(hpad + (size_t)b * PIMG, ucat, 128, y, x0, n0, stage, acc);
  const size_t rowb = ((size_t)(b * 56) + y) * 64;
#pragma unroll
  for (int mf = 0; mf < 2; ++mf)
#pragma unroll
    for (int nf = 0; nf < 2; ++nf) {
      const int n = n0 + nf * 16 + (lane & 15);
#pragma unroll
      for (int r = 0; r < 4; ++r) {
        const int px = x0 + mf * 16 + 4 * (lane >> 4) + r;
        if (px < 56) {
          float a = bf2f(wx[(rowb + px) * 192 + n]) + acc[mf][nf][r];
          float s = 1.f / (1.f + __expf(-a));
          if (n < 64) {
            zb[(rowb + px) * 64 + n] = s;
          } else {
            const int ci = n - 64;
            float rh = s * hstate[(rowb + px) * 64 + ci];
            const int gx = px + 1;
            rhpad[(size_t)b * PIMG + (size_t)(y + 1) * PIX + gx * 64 +
                  (((ci >> 3) ^ (gx & 7)) << 3) + (ci & 7)] = f2bf(rh);
          }
        }
      }
    }
}

__device__ __forceinline__ void do_convC(
    const u16* __restrict__ rhpad, const u16* __restrict__ ccat,
    const u16* __restrict__ wx, const float* __restrict__ zb,
    float* __restrict__ hstate, u16* __restrict__ hpad,
    float* __restrict__ out, int t, int u, u16* stage, float (*ldt)[16][33]) {
  const int x0 = (u & 1) * 32, row = u >> 1;
  const int y = row % 56, b = row / 56;
  const int lane = threadIdx.x & 63;
  const int wv = threadIdx.x >> 6;
  const int n0 = __builtin_amdgcn_readfirstlane(wv * 16);
  f32x4 acc[2][1];
  acc[0][0] = (f32x4){0.f, 0.f, 0.f, 0.f};
  acc[1][0] = (f32x4){0.f, 0.f, 0.f, 0.f};
  conv_core<1>(rhpad + (size_t)b * PIMG, ccat, 64, y, x0, n0, stage, acc);
  const size_t rowb = ((size_t)(b * 56) + y) * 64;
  const int n = n0 + (lane & 15);
#pragma unroll
  for (int mf = 0; mf < 2; ++mf)
#pragma unroll
    for (int r = 0; r < 4; ++r) {
      const int px = x0 + mf * 16 + 4 * (lane >> 4) + r;
      if (px < 56) {
        float a = bf2f(wx[(rowb + px) * 192 + 128 + n]) + acc[mf][0][r];
        float htil = tanhf(a);
        float z = zb[(rowb + px) * 64 + n];
        float ho = hstate[(rowb + px) * 64 + n];
        float hn = fmaf(z, htil - ho, ho);
        hstate[(rowb + px) * 64 + n] = hn;
        const int gx = px + 1;
        hpad[(size_t)b * PIMG + (size_t)(y + 1) * PIX + gx * 64 +
             (((n >> 3) ^ (gx & 7)) << 3) + (n & 7)] = f2bf(hn);
        ldt[wv][lane & 15][mf * 16 + 4 * (lane >> 4) + r] = hn;
      }
    }
  __syncthreads();
  const int xl = lane & 31;
  const int px = x0 + xl;
  if (px < 56) {
#pragma unroll
    for (int cc = 0; cc < 8; ++cc) {
      const int ch = (lane >> 5) * 8 + cc;
      float v = ldt[wv][ch][xl];
      out[(((size_t)(b * 16 + t)) * 64 + n0 + ch) * 3136 + y * 56 + px] = v;
      if (t == 15)
        out[HL_OFF + ((size_t)(b * 64) + n0 + ch) * 3136 + y * 56 + px] = v;
    }
  }
}

// ---- init helpers (row-granular, block bid -> row bid) ---------------------
__device__ __forceinline__ void xprep_row(const float* __restrict__ x,
                                          u16* __restrict__ dst, int t,
                                          float (*tx)[57]) {
  __syncthreads();
  const int row = blockIdx.x;
  const int y = row % 56, b = row / 56;
  const int tid = threadIdx.x;
  for (int i = tid; i < 64 * 56; i += 256) {
    int ci = i / 56, px = i % 56;
    tx[ci][px] = x[((size_t)(b * 16 + t) * 64 + ci) * 3136 + y * 56 + px];
  }
  __syncthreads();
  const size_t pb = (size_t)b * PIMG + (size_t)(y + 1) * PIX;
  for (int i = tid; i < 56 * 64; i += 256) {
    int px = i / 64, ci = i % 64;
    int gx = px + 1;
    dst[pb + gx * 64 + (((ci >> 3) ^ (gx & 7)) << 3) + (ci & 7)] =
        f2bf(tx[ci][px]);
  }
}

__device__ __forceinline__ void hinit_row(const float* __restrict__ h,
                                          u16* __restrict__ hpad,
                                          float* __restrict__ hstate,
                                          float (*tx)[57]) {
  __syncthreads();
  const int row = blockIdx.x;
  const int y = row % 56, b = row / 56;
  const int tid = threadIdx.x;
  for (int i = tid; i < 64 * 56; i += 256) {
    int ci = i / 56, px = i % 56;
    tx[ci][px] = h[((size_t)(b * 64) + ci) * 3136 + y * 56 + px];
  }
  __syncthreads();
  const size_t pb = (size_t)b * PIMG + (size_t)(y + 1) * PIX;
  const size_t sb = ((size_t)(b * 56) + y) * 64;
  for (int i = tid; i < 56 * 64; i += 256) {
    int px = i / 64, ci = i % 64;
    float v = tx[ci][px];
    int gx = px + 1;
    hpad[pb + gx * 64 + (((ci >> 3) ^ (gx & 7)) << 3) + (ci & 7)] = f2bf(v);
    hstate[(sb + px) * 64 + ci] = v;
  }
}

__device__ __forceinline__ void wprep_all(const float* __restrict__ W,
                                          const float* __restrict__ U,
                                          const float* __restrict__ C,
                                          u16* __restrict__ wcat) {
  for (int i = blockIdx.x * 256 + threadIdx.x; i < 221184; i += NBLK * 256) {
    float v;
    if (i < 110592) {
      int plane = i / 12288, rem = i % 12288, o = rem / 64, ci = rem % 64;
      v = W[(size_t)(o * 64 + ci) * 9 + plane];
    } else if (i < 184320) {
      int j = i - 110592;
      int plane = j / 8192, rem = j % 8192, o = rem / 64, ci = rem % 64;
      v = U[(size_t)(o * 64 + ci) * 9 + plane];
    } else {
      int j = i - 184320;
      int plane = j / 4096, rem = j % 4096, o = rem / 64, ci = rem % 64;
      v = C[(size_t)(o * 64 + ci) * 9 + plane];
    }
    wcat[i] = f2bf(v);
  }
}

// ---- the persistent kernel -------------------------------------------------
__global__ __launch_bounds__(256, 2) void gru_all(
    const float* __restrict__ x, const float* __restrict__ h,
    const float* __restrict__ W, const float* __restrict__ U,
    const float* __restrict__ C, float* __restrict__ out, void* wsv) {
  __shared__ u16 s_stage[6528];       // 3*34*64
  __shared__ float s_ldt[4][16][33];
  __shared__ float s_tx[64][57];

  u16* ws = (u16*)wsv;
  u16* xb0 = ws;
  u16* xb1 = xb0 + (size_t)8 * PIMG;
  u16* hpad = xb1 + (size_t)8 * PIMG;
  u16* rhpad = hpad + (size_t)8 * PIMG;
  unsigned* bar = (unsigned*)(rhpad + (size_t)8 * PIMG);
  u16* wcat = (u16*)((char*)bar + 64);
  u16* wx0 = wcat + 221184;
  u16* wx1 = wx0 + 5505024;
  float* zb = (float*)(wx1 + 5505024);
  float* hstate = zb + 1835008;

  const int bid = blockIdx.x;

  // P1: weights repack + h init + xpad(0)
  wprep_all(W, U, C, wcat);
  hinit_row(h, hpad, hstate, s_tx);
  xprep_row(x, xb0, 0, s_tx);
  gridbar(bar);

  // P2: wx(0) = conv(x0, W)
#pragma unroll 1
  for (int u = bid; u < 896; u += NBLK) do_convW(xb0, wcat, wx0, u, s_stage);
  gridbar(bar);

#pragma unroll 1
  for (int t = 0; t < 16; ++t) {
    const u16* xnxt = (t & 1) ? xb0 : xb1;   // buffer for xpad(t+1)
    u16* xnxt_w = (t & 1) ? xb0 : xb1;
    const u16* wxc = (t & 1) ? wx1 : wx0;    // wx(t)
    u16* wxn = (t & 1) ? wx0 : wx1;          // wx(t+1)

    // phase A: convU(t) ; xprep(t+1)
#pragma unroll 1
    for (int u = bid; u < 896; u += NBLK)
      do_convU(hpad, wcat + 110592, wxc, hstate, zb, rhpad, u, s_stage);
    if (t + 1 < 16) xprep_row(x, xnxt_w, t + 1, s_tx);
    gridbar(bar);

    // phase B: convC(t)+combine ; convW(t+1)
#pragma unroll 1
    for (int u = bid; u < 896; u += NBLK)
      do_convC(rhpad, wcat + 184320, wxc, zb, hstate, hpad, out, t, u, s_stage,
               s_ldt);
    if (t + 1 < 16) {
#pragma unroll 1
      for (int u = bid; u < 896; u += NBLK)
        do_convW(xnxt, wcat, wxn, u, s_stage);
    }
    gridbar(bar);
  }
}

extern "C" void kernel_launch(void* const* d_in, const int* in_sizes, int n_in,
                              void* d_out, int out_size, void* d_ws,
                              size_t ws_size, hipStream_t stream) {
  const float* x = (const float*)d_in[0];
  const float* h = (const float*)d_in[1];
  const float* W = (const float*)d_in[2];
  const float* U = (const float*)d_in[3];
  const float* C = (const float*)d_in[4];

  // zero: 4 padded images (borders must stay 0) + barrier vars
  hipMemsetAsync(d_ws, 0, (size_t)4 * 8 * PIMG * 2 + 64, stream);
  gru_all<<<NBLK, 256, 0, stream>>>(x, h, W, U, C, (float*)d_out, d_ws);
}

// Round 5
// 1197.264 us; speedup vs baseline: 6.0961x; 6.0961x over previous
//
#include <hip/hip_runtime.h>
#include <math.h>

// GRU-RCN bf16 MFMA, multi-kernel (CP-managed coherence — NO in-kernel grid
// barriers; round-4 showed per-phase L2 flush storms cost 5x).
// B=8,T=16,C=Oh=64,HxW=56x56, 3x3 SAME.
// Structure: x-path (h-independent) batched in groups of 4 timesteps:
//   per group g: xprep4 (x->xpad ring), convW4 (wx ring, 3584 blocks);
//   then 4x { convU(t): z, r*h ; convC(t): h_new, out }.
// Layouts:
//   padded imgs: bf16 [58][66][64ci], 16B ci-slices XOR-swizzled by (col&7).
//   xring: [slot4][b][PIMG]; wx ring: bf16 [b][slot4][y56][px64][192]
//   wcat: bf16 [plane(ky*3+kx)][o][ci] (W:192, U:128, C:64)
//   zb, hstate: f32 [b][y][px64][64]

#define PIX 4224                   // 66*64 u16 per padded row
#define PIMG 244992                // 58*PIX u16 per padded image
#define BIMG ((size_t)8 * PIMG)    // u16 per slot (8 batches)
#define HL_OFF ((size_t)25690112)  // 8*16*64*3136 floats

typedef unsigned short u16;
typedef __attribute__((ext_vector_type(8))) __bf16 bf16x8;
typedef __attribute__((ext_vector_type(4))) float f32x4;

__device__ __forceinline__ float bf2f(u16 u) {
  unsigned v = ((unsigned)u) << 16;
  float f;
  __builtin_memcpy(&f, &v, 4);
  return f;
}
__device__ __forceinline__ u16 f2bf(float f) {
  unsigned u;
  __builtin_memcpy(&u, &f, 4);
  u = (u + 0x7FFFu + ((u >> 16) & 1u)) >> 16;  // RNE
  return (u16)u;
}
__device__ __forceinline__ void gll16(const void* g, void* l) {
  __builtin_amdgcn_global_load_lds(
      (const __attribute__((address_space(1))) void*)g,
      (__attribute__((address_space(3))) void*)l, 16, 0, 0);
}

// ---- conv core: D[32px x NF*16ch per wave] = conv3x3(img, wb), K=576 -------
// A-frag: lane l -> A[m=l&15][k=8*(l>>4)+j]; B: lane l -> Wt[n=l&15][k..]
template <int NF>
__device__ __forceinline__ void conv_core(const u16* __restrict__ img,
                                          const u16* __restrict__ wb,
                                          const int NCH, const int y,
                                          const int x0, const int n0,
                                          u16* stage, f32x4 (&acc)[2][NF]) {
  const int lane = threadIdx.x & 63;
  const int wv = threadIdx.x >> 6;
  const u16* wrow = wb + (size_t)(n0 + (lane & 15)) * 64 + ((lane >> 4) * 8);
#define BPTR(ky, kx, kc, nf) \
  (wrow + (size_t)((ky) * 3 + (kx)) * NCH * 64 + (nf) * 1024 + (kc) * 32)
  bf16x8 bcur[3][NF], bnxt[3][NF];
#pragma unroll
  for (int kx = 0; kx < 3; ++kx)
#pragma unroll
    for (int nf = 0; nf < NF; ++nf)
      bcur[kx][nf] = *(const bf16x8*)BPTR(0, kx, 0, nf);

  // stage strip rows y..y+2, cols x0..x0+33 (34px x 128B per row)
#pragma unroll
  for (int i = wv; i < 15; i += 4) {
    const int r = i / 5, k = i % 5;
    const u16* g = img + (size_t)(y + r) * PIX + x0 * 64 + k * 512 + lane * 8;
    u16* l = stage + r * 2176 + k * 512;
    if (k < 4 || lane < 16) gll16(g, l);
  }
  asm volatile("s_waitcnt vmcnt(0)" ::: "memory");
  __syncthreads();

#pragma unroll 1
  for (int kk = 0; kk < 6; ++kk) {
    const int ky = kk >> 1, kc = kk & 1;
    if (kk < 5) {
      const int ky2 = (kk + 1) >> 1, kc2 = (kk + 1) & 1;
#pragma unroll
      for (int kx = 0; kx < 3; ++kx)
#pragma unroll
        for (int nf = 0; nf < NF; ++nf)
          bnxt[kx][nf] = *(const bf16x8*)BPTR(ky2, kx, kc2, nf);
    }
    bf16x8 afr[2][3];
#pragma unroll
    for (int mf = 0; mf < 2; ++mf)
#pragma unroll
      for (int kx = 0; kx < 3; ++kx) {
        const int p = mf * 16 + (lane & 15) + kx;
        const int sl = (kc * 4 + (lane >> 4)) ^ (p & 7);
        afr[mf][kx] = *(const bf16x8*)(stage + (ky * 34 + p) * 64 + sl * 8);
      }
#pragma unroll
    for (int kx = 0; kx < 3; ++kx)
#pragma unroll
      for (int mf = 0; mf < 2; ++mf)
#pragma unroll
        for (int nf = 0; nf < NF; ++nf)
          acc[mf][nf] = __builtin_amdgcn_mfma_f32_16x16x32_bf16(
              afr[mf][kx], bcur[kx][nf], acc[mf][nf], 0, 0, 0);
#pragma unroll
    for (int kx = 0; kx < 3; ++kx)
#pragma unroll
      for (int nf = 0; nf < NF; ++nf)
        bcur[kx][nf] = bnxt[kx][nf];
  }
#undef BPTR
}

// ---- weight repack: [o][ci][3][3] f32 -> wcat bf16 [plane][o][ci] ----------
__global__ __launch_bounds__(256) void wprep_k(const float* __restrict__ W,
                                               const float* __restrict__ U,
                                               const float* __restrict__ C,
                                               u16* __restrict__ wcat) {
  int i = blockIdx.x * 256 + threadIdx.x;
  if (i >= 221184) return;
  float v;
  if (i < 110592) {  // W: [9][192][64]
    int plane = i / 12288, rem = i % 12288, o = rem / 64, ci = rem % 64;
    v = W[(size_t)(o * 64 + ci) * 9 + plane];
  } else if (i < 184320) {  // U: [9][128][64]
    int j = i - 110592;
    int plane = j / 8192, rem = j % 8192, o = rem / 64, ci = rem % 64;
    v = U[(size_t)(o * 64 + ci) * 9 + plane];
  } else {  // C: [9][64][64]
    int j = i - 184320;
    int plane = j / 4096, rem = j % 4096, o = rem / 64, ci = rem % 64;
    v = C[(size_t)(o * 64 + ci) * 9 + plane];
  }
  wcat[i] = f2bf(v);
}

// ---- h init: NCHW f32 -> hpad bf16 (swizzled) + hstate f32 NHWC ------------
__global__ __launch_bounds__(256) void hinit_k(const float* __restrict__ h,
                                               u16* __restrict__ hpad,
                                               float* __restrict__ hstate) {
  __shared__ float t[64][57];
  const int y = blockIdx.x, b = blockIdx.y;
  const int tid = threadIdx.x;
  for (int i = tid; i < 64 * 56; i += 256) {
    int ci = i / 56, xx = i % 56;
    t[ci][xx] = h[((size_t)(b * 64) + ci) * 3136 + y * 56 + xx];
  }
  __syncthreads();
  const size_t pb = (size_t)b * PIMG + (size_t)(y + 1) * PIX;
  const size_t sb = ((size_t)(b * 56) + y) * 64;
  for (int i = tid; i < 56 * 64; i += 256) {
    int px = i / 64, ci = i % 64;
    float v = t[ci][px];
    int gx = px + 1;
    hpad[pb + gx * 64 + (((ci >> 3) ^ (gx & 7)) << 3) + (ci & 7)] = f2bf(v);
    hstate[(sb + px) * 64 + ci] = v;
  }
}

// ---- xprep4: x_t (4 steps) NCHW f32 -> xring bf16 (swizzled) ---------------
__global__ __launch_bounds__(256) void xprep4_k(const float* __restrict__ x,
                                                u16* __restrict__ xring,
                                                int t0) {
  __shared__ float tt[64][57];
  const int y = blockIdx.x, b = blockIdx.y, t = t0 + blockIdx.z;
  const int tid = threadIdx.x;
  for (int i = tid; i < 64 * 56; i += 256) {
    int ci = i / 56, px = i % 56;
    tt[ci][px] = x[((size_t)(b * 16 + t) * 64 + ci) * 3136 + y * 56 + px];
  }
  __syncthreads();
  const size_t pb =
      (size_t)(t & 3) * BIMG + (size_t)b * PIMG + (size_t)(y + 1) * PIX;
  for (int i = tid; i < 56 * 64; i += 256) {
    int px = i / 64, ci = i % 64;
    int gx = px + 1;
    xring[pb + gx * 64 + (((ci >> 3) ^ (gx & 7)) << 3) + (ci & 7)] =
        f2bf(tt[ci][px]);
  }
}

// ---- convW4: wx(t..t+3) = conv(x, W[192]) -> bf16 ring ---------------------
__global__ __launch_bounds__(256) void convW_k(const u16* __restrict__ xring,
                                               const u16* __restrict__ wcat,
                                               u16* __restrict__ wx, int t0) {
  __shared__ u16 stage[6528];
  const int x0 = blockIdx.x * 32, y = blockIdx.y;
  const int b = blockIdx.z & 7, t = t0 + (blockIdx.z >> 3), slot = t & 3;
  const int lane = threadIdx.x & 63;
  const int n0 = __builtin_amdgcn_readfirstlane((threadIdx.x >> 6) * 48);
  f32x4 acc[2][3];
#pragma unroll
  for (int mf = 0; mf < 2; ++mf)
#pragma unroll
    for (int nf = 0; nf < 3; ++nf) acc[mf][nf] = (f32x4){0.f, 0.f, 0.f, 0.f};
  conv_core<3>(xring + (size_t)slot * BIMG + (size_t)b * PIMG, wcat, 192, y,
               x0, n0, stage, acc);

  const size_t rowb = ((size_t)(b * 4 + slot) * 56 + y) * 64;
#pragma unroll
  for (int mf = 0; mf < 2; ++mf)
#pragma unroll
    for (int nf = 0; nf < 3; ++nf) {
      const int n = n0 + nf * 16 + (lane & 15);
#pragma unroll
      for (int r = 0; r < 4; ++r) {
        const int px = x0 + mf * 16 + 4 * (lane >> 4) + r;
        wx[(rowb + px) * 192 + n] = f2bf(acc[mf][nf][r]);
      }
    }
}

// ---- convU: uh = conv(h, U[128]); z=sig(wx_z+uh_z); rh=sig(wx_r+uh_r)*h ----
__global__ __launch_bounds__(256) void convU_k(
    const u16* __restrict__ hpad, const u16* __restrict__ ucat,
    const u16* __restrict__ wx, const float* __restrict__ hstate,
    float* __restrict__ zb, u16* __restrict__ rhpad, int t) {
  __shared__ u16 stage[6528];
  const int x0 = blockIdx.x * 32, y = blockIdx.y, b = blockIdx.z;
  const int slot = t & 3;
  const int lane = threadIdx.x & 63;
  const int n0 = __builtin_amdgcn_readfirstlane((threadIdx.x >> 6) * 32);
  f32x4 acc[2][2];
#pragma unroll
  for (int mf = 0; mf < 2; ++mf)
#pragma unroll
    for (int nf = 0; nf < 2; ++nf) acc[mf][nf] = (f32x4){0.f, 0.f, 0.f, 0.f};
  conv_core<2>(hpad + (size_t)b * PIMG, ucat, 128, y, x0, n0, stage, acc);

  const size_t wrow = ((size_t)(b * 4 + slot) * 56 + y) * 64;
  const size_t rowb = ((size_t)(b * 56) + y) * 64;
#pragma unroll
  for (int mf = 0; mf < 2; ++mf)
#pragma unroll
    for (int nf = 0; nf < 2; ++nf) {
      const int n = n0 + nf * 16 + (lane & 15);
#pragma unroll
      for (int r = 0; r < 4; ++r) {
        const int px = x0 + mf * 16 + 4 * (lane >> 4) + r;
        if (px < 56) {
          float a = bf2f(wx[(wrow + px) * 192 + n]) + acc[mf][nf][r];
          float s = 1.f / (1.f + __expf(-a));
          if (n < 64) {
            zb[(rowb + px) * 64 + n] = s;
          } else {
            const int ci = n - 64;
            float rh = s * hstate[(rowb + px) * 64 + ci];
            const int gx = px + 1;
            rhpad[(size_t)b * PIMG + (size_t)(y + 1) * PIX + gx * 64 +
                  (((ci >> 3) ^ (gx & 7)) << 3) + (ci & 7)] = f2bf(rh);
          }
        }
      }
    }
}

// ---- convC: cc = conv(rh, C[64]); h_new = (1-z)h + z tanh(wx_c + cc) -------
__global__ __launch_bounds__(256) void convC_k(
    const u16* __restrict__ rhpad, const u16* __restrict__ ccat,
    const u16* __restrict__ wx, const float* __restrict__ zb,
    float* __restrict__ hstate, u16* __restrict__ hpad,
    float* __restrict__ out, int t) {
  __shared__ u16 stage[6528];
  __shared__ float ldt[4][16][33];
  const int x0 = blockIdx.x * 32, y = blockIdx.y, b = blockIdx.z;
  const int slot = t & 3;
  const int lane = threadIdx.x & 63;
  const int wv = threadIdx.x >> 6;
  const int n0 = __builtin_amdgcn_readfirstlane(wv * 16);
  f32x4 acc[2][1];
  acc[0][0] = (f32x4){0.f, 0.f, 0.f, 0.f};
  acc[1][0] = (f32x4){0.f, 0.f, 0.f, 0.f};
  conv_core<1>(rhpad + (size_t)b * PIMG, ccat, 64, y, x0, n0, stage, acc);

  const size_t wrow = ((size_t)(b * 4 + slot) * 56 + y) * 64;
  const size_t rowb = ((size_t)(b * 56) + y) * 64;
  const int n = n0 + (lane & 15);
#pragma unroll
  for (int mf = 0; mf < 2; ++mf)
#pragma unroll
    for (int r = 0; r < 4; ++r) {
      const int px = x0 + mf * 16 + 4 * (lane >> 4) + r;
      if (px < 56) {
        float a = bf2f(wx[(wrow + px) * 192 + 128 + n]) + acc[mf][0][r];
        float htil = tanhf(a);
        float z = zb[(rowb + px) * 64 + n];
        float ho = hstate[(rowb + px) * 64 + n];
        float hn = fmaf(z, htil - ho, ho);
        hstate[(rowb + px) * 64 + n] = hn;
        const int gx = px + 1;
        hpad[(size_t)b * PIMG + (size_t)(y + 1) * PIX + gx * 64 +
             (((n >> 3) ^ (gx & 7)) << 3) + (n & 7)] = f2bf(hn);
        ldt[wv][lane & 15][mf * 16 + 4 * (lane >> 4) + r] = hn;
      }
    }
  __syncthreads();
  const int xl = lane & 31;
  const int px = x0 + xl;
  if (px < 56) {
#pragma unroll
    for (int cc = 0; cc < 8; ++cc) {
      const int ch = (lane >> 5) * 8 + cc;
      float v = ldt[wv][ch][xl];
      out[(((size_t)(b * 16 + t)) * 64 + n0 + ch) * 3136 + y * 56 + px] = v;
      if (t == 15)
        out[HL_OFF + ((size_t)(b * 64) + n0 + ch) * 3136 + y * 56 + px] = v;
    }
  }
}

extern "C" void kernel_launch(void* const* d_in, const int* in_sizes, int n_in,
                              void* d_out, int out_size, void* d_ws,
                              size_t ws_size, hipStream_t stream) {
  const float* x = (const float*)d_in[0];
  const float* h = (const float*)d_in[1];
  const float* W = (const float*)d_in[2];
  const float* U = (const float*)d_in[3];
  const float* C = (const float*)d_in[4];
  float* out = (float*)d_out;

  u16* ws_u = (u16*)d_ws;
  u16* xring = ws_u;                    // 4 slots x 8 b x PIMG = 7,839,744 u16
  u16* hpad = xring + 4 * BIMG;         // 1,959,936
  u16* rhpad = hpad + BIMG;             // 1,959,936
  u16* wcat = rhpad + BIMG;             // 221,184
  u16* wxr = wcat + 221184;             // 8b x 4slot x 56y x 64px x 192 = 22,020,096
  float* zb = (float*)(wxr + 22020096); // 1,835,008 f32
  float* hstate = zb + 1835008;         // 1,835,008 f32  (total ~82.7 MB)

  // zero padded images once (borders stay 0; interiors rewritten every reuse)
  hipMemsetAsync(d_ws, 0, (size_t)6 * BIMG * sizeof(u16), stream);
  wprep_k<<<864, 256, 0, stream>>>(W, U, C, wcat);
  hinit_k<<<dim3(56, 8), 256, 0, stream>>>(h, hpad, hstate);

  dim3 ugrid(2, 56, 8);
  for (int g = 0; g < 4; ++g) {
    const int t0 = g * 4;
    xprep4_k<<<dim3(56, 8, 4), 256, 0, stream>>>(x, xring, t0);
    convW_k<<<dim3(2, 56, 32), 256, 0, stream>>>(xring, wcat, wxr, t0);
    for (int tt = 0; tt < 4; ++tt) {
      const int t = t0 + tt;
      convU_k<<<ugrid, 256, 0, stream>>>(hpad, wcat + 110592, wxr, hstate, zb,
                                         rhpad, t);
      convC_k<<<ugrid, 256, 0, stream>>>(rhpad, wcat + 184320, wxr, zb, hstate,
                                         hpad, out, t);
    }
  }
}